// Round 5
// baseline (3291.998 us; speedup 1.0000x reference)
//
#include <hip/hip_runtime.h>
#include <stdint.h>

#define BB 32
#define LL 1024
#define NW 512
#define HH 768
#define HID 384
#define G4 1536   // 4*HID
#define EE 4
#define DLL 128
#define GIN 896   // H+DL
#define CWG 12    // column-group WGs per direction
#define WGC 32    // h-cols per WG
#define HPAD 392  // padded LDS row stride (shorts)

typedef __attribute__((ext_vector_type(8))) short short8;
typedef __attribute__((ext_vector_type(4))) float f32x4;

__device__ __forceinline__ float bf2f(short s){
  union { unsigned int u; float f; } v; v.u = ((unsigned int)(unsigned short)s) << 16; return v.f;
}
__device__ __forceinline__ short f2bf(float f){
  union { float f; unsigned int u; } v; v.f = f;
  unsigned int r = v.u + 0x7fffu + ((v.u >> 16) & 1u);
  return (short)(r >> 16);
}
__device__ __forceinline__ float sigm(float x){ return 1.f / (1.f + __expf(-x)); }
__device__ __forceinline__ float ftanh(float x){ float e = __expf(2.f * x); return 1.f - 2.f / (e + 1.f); }
__device__ __forceinline__ float pick4(int k, float v0, float v1, float v2, float v3){
  float a = (k & 1) ? v1 : v0;
  float b = (k & 1) ? v3 : v2;
  return (k & 2) ? b : a;
}

__device__ __forceinline__ void gload16(const void* g, void* l){
  __builtin_amdgcn_global_load_lds(
      (const __attribute__((address_space(1))) unsigned int*)g,
      (__attribute__((address_space(3))) unsigned int*)l, 16, 0, 0);
}

// ---------------- zero flags ----------------
__global__ void k_zero(int* flags, int n){
  int i = blockIdx.x * 256 + threadIdx.x;
  if (i < n) flags[i] = 0;
}

// ---------------- f32 -> bf16 convert ----------------
__global__ void k_f2bf(const float* in, short* out, int n){
  int i = blockIdx.x * blockDim.x + threadIdx.x;
  int st = gridDim.x * blockDim.x;
  for (; i < n; i += st) out[i] = f2bf(in[i]);
}

// ---------------- segment mean pooling ----------------
__global__ __launch_bounds__(256) void k_segmean(const float* __restrict__ tok,
                                                 const int* __restrict__ wmap,
                                                 short* __restrict__ we_bf){
  int blk = blockIdx.x;
  int b = blk >> 9;          // / NW
  int w = blk & 511;
  const int* m = wmap + b * LL;
  int lo = 0, hi = LL;
  while (lo < hi){ int mid = (lo + hi) >> 1; if (m[mid] < w) lo = mid + 1; else hi = mid; }
  int s = lo;
  int lo2 = s, hi2 = LL;
  while (lo2 < hi2){ int mid = (lo2 + hi2) >> 1; if (m[mid] <= w) lo2 = mid + 1; else hi2 = mid; }
  int e = lo2;
  float cnt = (float)(e - s);
  float denom = fmaxf(cnt, 1.f);
  for (int j = threadIdx.x; j < HH; j += 256){
    float acc = 0.f;
    for (int r = s; r < e; ++r) acc += tok[((size_t)b * LL + r) * HH + j];
    we_bf[((size_t)b * NW + w) * HH + j] = f2bf(acc / denom);
  }
}

// ---------------- GEMM: C[M,N] = A[M,K](bf16) * W[N,K]^T(bf16) + b1[n] + b2[n] ----------------
__global__ __launch_bounds__(256) void k_gemm_bt(const short* __restrict__ Abf,
                                                 const short* __restrict__ Wbf,
                                                 const float* __restrict__ b1,
                                                 const float* __restrict__ b2,
                                                 float* __restrict__ Cf,
                                                 int M, int N, int K){
  __shared__ __attribute__((aligned(16))) short As[128 * 32];
  __shared__ __attribute__((aligned(16))) short Bs[128 * 32];
  int ntiles = N >> 7;
  int m0 = (blockIdx.x / ntiles) << 7;
  int n0 = (blockIdx.x % ntiles) << 7;
  int tid = threadIdx.x, lane = tid & 63, wv = tid >> 6;
  int wm = (wv >> 1) << 6, wn = (wv & 1) << 6;
  f32x4 acc[4][4] = {};
  for (int kk = 0; kk < K; kk += 32){
#pragma unroll
    for (int q = 0; q < 2; ++q){
      int e = q * 256 + tid;        // 16B granule: row = e/4, col = (e&3)*8 shorts
      int row = e >> 2, col = (e & 3) << 3;
      gload16(Abf + (size_t)(m0 + row) * K + kk + col, As + e * 8);
      gload16(Wbf + (size_t)(n0 + row) * K + kk + col, Bs + e * 8);
    }
    __syncthreads();
    short8 af[4], bfr[4];
#pragma unroll
    for (int x = 0; x < 4; ++x){
      af[x]  = *(const short8*)(As + (wm + x * 16 + (lane & 15)) * 32 + ((lane >> 4) << 3));
      bfr[x] = *(const short8*)(Bs + (wn + x * 16 + (lane & 15)) * 32 + ((lane >> 4) << 3));
    }
#pragma unroll
    for (int x = 0; x < 4; ++x)
#pragma unroll
      for (int y = 0; y < 4; ++y)
        acc[x][y] = __builtin_amdgcn_mfma_f32_16x16x32_bf16(af[x], bfr[y], acc[x][y], 0, 0, 0);
    __syncthreads();
  }
#pragma unroll
  for (int x = 0; x < 4; ++x)
#pragma unroll
    for (int y = 0; y < 4; ++y)
#pragma unroll
      for (int i = 0; i < 4; ++i){
        int mm = m0 + wm + x * 16 + ((lane >> 4) << 2) + i;
        int nn = n0 + wn + y * 16 + (lane & 15);
        Cf[(size_t)mm * N + nn] = acc[x][y][i] + b1[nn] + b2[nn];
      }
}

// ---------------- BiLSTM: persistent, in-wave gates (no pre[] exchange) ----------------
// 12 WGs/dir x 512 threads (8 waves). Wave wv owns 4 cols; its 16 MFMA B-rows are
// gate-interleaved: lane fr -> gate=fr>>2, col=wv*4+(fr&3). After MFMA each lane quad
// holds i,f,g,o for the same (b,col) -> gate gather via 3x shfl_xor, no LDS, no barrier.
__global__ __launch_bounds__(512) void k_lstm(const float* __restrict__ xg_f,
                                              const float* __restrict__ xg_b,
                                              const short* __restrict__ whh_f,
                                              const short* __restrict__ whh_b,
                                              short* __restrict__ hbuf,
                                              short* __restrict__ hcat,
                                              int* __restrict__ flags){
  int bx = blockIdx.x;
  int dir = bx / CWG;
  int cg  = bx % CWG;
  int tid = threadIdx.x, lane = tid & 63, wv = tid >> 6;
  int q = lane >> 4, fr = lane & 15;
  int gate = fr >> 2, cQ = fr & 3;
  int ncol = cg * WGC + wv * 4 + cQ;      // column within HID
  int n = gate * HID + ncol;              // gate-row within G4
  const float* xg  = dir ? xg_b : xg_f;
  const short* whh = dir ? whh_b : whh_f;

  // resident Whh B-fragment: gate-interleaved 16 rows x K=384 -> 12 k-steps, 48 VGPRs
  short8 bfrag[12];
  {
    const short* wr = whh + (size_t)n * HID + q * 8;
#pragma unroll
    for (int ks = 0; ks < 12; ++ks) bfrag[ks] = *(const short8*)(wr + ks * 32);
  }

  __shared__ __attribute__((aligned(16))) short hs[32 * HPAD];  // staged h(t-1), 24.5 KB

  float cLo[4] = {0.f, 0.f, 0.f, 0.f};
  float cHi[4] = {0.f, 0.f, 0.f, 0.f};
  int pc = fr;                               // poll lane index
  int* flg = flags + dir * NW * 16;
  short* hb0 = hbuf + (size_t)dir * 2 * BB * HID;

  for (int t = 0; t < NW; ++t){
    int t_act = dir ? (NW - 1 - t) : t;
    // xg prefetch (independent of h) — its latency merges into the poll's vmcnt
    float xgv[8];
#pragma unroll
    for (int i = 0; i < 4; ++i){
      xgv[i]     = xg[((size_t)(q * 4 + i) * NW + t_act) * G4 + n];
      xgv[4 + i] = xg[((size_t)(16 + q * 4 + i) * NW + t_act) * G4 + n];
    }
    f32x4 aL0 = {}, aL1 = {}, aH0 = {}, aH1 = {};
    if (t > 0){
      // all-wave ballot poll on the 12 per-cg flags (one 64B line)
      const int* fp = flg + (t - 1) * 16 + pc;
      for (;;){
        int v;
        asm volatile("global_load_dword %0, %1, off sc0 sc1\n\ts_waitcnt vmcnt(0)"
                     : "=v"(v) : "v"(fp) : "memory");
        if (__all(v != 0 || pc >= CWG)) break;
      }
      // stage h(t-1) -> LDS, coalesced: 3 x b128 MALL-coherent loads per thread
      const short* hp = hb0 + ((t - 1) & 1) * BB * HID;
      short8 sv0, sv1, sv2;
      {
        const short* s0 = hp + (0 * 512 + tid) * 8;
        const short* s1 = hp + (1 * 512 + tid) * 8;
        const short* s2 = hp + (2 * 512 + tid) * 8;
        asm volatile("global_load_dwordx4 %0, %1, off sc0 sc1" : "=v"(sv0) : "v"(s0) : "memory");
        asm volatile("global_load_dwordx4 %0, %1, off sc0 sc1" : "=v"(sv1) : "v"(s1) : "memory");
        asm volatile("global_load_dwordx4 %0, %1, off sc0 sc1" : "=v"(sv2) : "v"(s2) : "memory");
        asm volatile("s_waitcnt vmcnt(0)" ::: "memory");
      }
      { int gi = 0 * 512 + tid; *(short8*)(hs + (gi / 48) * HPAD + (gi % 48) * 8) = sv0; }
      { int gi = 1 * 512 + tid; *(short8*)(hs + (gi / 48) * HPAD + (gi % 48) * 8) = sv1; }
      { int gi = 2 * 512 + tid; *(short8*)(hs + (gi / 48) * HPAD + (gi % 48) * 8) = sv2; }
      __syncthreads();   // barrier A: staging complete
#pragma unroll
      for (int ks = 0; ks < 12; ++ks){
        short8 a0 = *(const short8*)(hs + fr * HPAD + ks * 32 + q * 8);
        short8 a1 = *(const short8*)(hs + (fr + 16) * HPAD + ks * 32 + q * 8);
        if (ks & 1){
          aL1 = __builtin_amdgcn_mfma_f32_16x16x32_bf16(a0, bfrag[ks], aL1, 0, 0, 0);
          aH1 = __builtin_amdgcn_mfma_f32_16x16x32_bf16(a1, bfrag[ks], aH1, 0, 0, 0);
        } else {
          aL0 = __builtin_amdgcn_mfma_f32_16x16x32_bf16(a0, bfrag[ks], aL0, 0, 0, 0);
          aH0 = __builtin_amdgcn_mfma_f32_16x16x32_bf16(a1, bfrag[ks], aH0, 0, 0, 0);
        }
      }
    }
    f32x4 aLo = aL0 + aL1;
    f32x4 aHi = aH0 + aH1;
    // in-wave gate gather + elementwise (each lane quad holds all 4 gates)
    unsigned int hLo[4], hHi[4];
#pragma unroll
    for (int i = 0; i < 4; ++i){
      float pl = aLo[i] + xgv[i];
      float ph = aHi[i] + xgv[4 + i];
      float l1 = __shfl_xor(pl, 4), l2 = __shfl_xor(pl, 8), l3 = __shfl_xor(pl, 12);
      float m1 = __shfl_xor(ph, 4), m2 = __shfl_xor(ph, 8), m3 = __shfl_xor(ph, 12);
      float giL = pick4(gate,     pl, l1, l2, l3);
      float gfL = pick4(gate ^ 1, pl, l1, l2, l3);
      float ggL = pick4(gate ^ 2, pl, l1, l2, l3);
      float goL = pick4(gate ^ 3, pl, l1, l2, l3);
      cLo[i] = sigm(gfL) * cLo[i] + sigm(giL) * ftanh(ggL);
      float hL = sigm(goL) * ftanh(cLo[i]);
      float giH = pick4(gate,     ph, m1, m2, m3);
      float gfH = pick4(gate ^ 1, ph, m1, m2, m3);
      float ggH = pick4(gate ^ 2, ph, m1, m2, m3);
      float goH = pick4(gate ^ 3, ph, m1, m2, m3);
      cHi[i] = sigm(gfH) * cHi[i] + sigm(giH) * ftanh(ggH);
      float hH = sigm(goH) * ftanh(cHi[i]);
      hLo[i] = (unsigned int)(unsigned short)f2bf(hL);
      hHi[i] = (unsigned int)(unsigned short)f2bf(hH);
    }
    short* hw = hb0 + (t & 1) * BB * HID;
    if (gate == 0){
#pragma unroll
      for (int i = 0; i < 4; ++i){
        short* pL = hw + (q * 4 + i) * HID + ncol;
        short* pH = hw + (16 + q * 4 + i) * HID + ncol;
        asm volatile("global_store_short %0, %1, off sc0 sc1" :: "v"(pL), "v"(hLo[i]) : "memory");
        asm volatile("global_store_short %0, %1, off sc0 sc1" :: "v"(pH), "v"(hHi[i]) : "memory");
      }
    } else if (gate == 1){
#pragma unroll
      for (int i = 0; i < 4; ++i){
        hcat[((size_t)(q * 4 + i) * NW + t_act) * HH + dir * HID + ncol] = (short)hLo[i];
        hcat[((size_t)(16 + q * 4 + i) * NW + t_act) * HH + dir * HID + ncol] = (short)hHi[i];
      }
    }
    asm volatile("s_waitcnt vmcnt(0)" ::: "memory");  // h stores ack'd at MALL
    __syncthreads();   // barrier C: all threads' stores ack'd
    if (tid == 0){
      int one = 1;
      int* fs = flg + t * 16 + cg;
      asm volatile("global_store_dword %0, %1, off sc0 sc1" :: "v"(fs), "v"(one) : "memory");
    }
  }
}

// ---------------- gate MLP + softmax (per batch row) ----------------
__global__ __launch_bounds__(256) void k_gate(const float* __restrict__ tok,
                                              const int* __restrict__ lids,
                                              const float* __restrict__ ltab,
                                              const float* __restrict__ W1,
                                              const float* __restrict__ b1v,
                                              const float* __restrict__ W2,
                                              const float* __restrict__ b2v,
                                              float* __restrict__ gate){
  __shared__ float gin[GIN];
  __shared__ float hid[HH];
  __shared__ float pr[EE];
  int b = blockIdx.x, tid = threadIdx.x;
  int lid = lids[b];
  for (int i = tid; i < GIN; i += 256)
    gin[i] = (i < HH) ? tok[(size_t)b * LL * HH + i] : ltab[lid * DLL + (i - HH)];
  __syncthreads();
  for (int j = tid; j < HH; j += 256){
    float a = b1v[j];
    const float* wr = W1 + (size_t)j * GIN;
    for (int k = 0; k < GIN; ++k) a += gin[k] * wr[k];
    hid[j] = fmaxf(a, 0.f);
  }
  __syncthreads();
  int wv = tid >> 6, lane = tid & 63;
  if (wv < EE){
    float p = 0.f;
    for (int k = lane; k < HH; k += 64) p += hid[k] * W2[wv * HH + k];
#pragma unroll
    for (int off = 32; off; off >>= 1) p += __shfl_down(p, off);
    if (lane == 0) pr[wv] = p + b2v[wv];
  }
  __syncthreads();
  if (tid == 0){
    float mx = fmaxf(fmaxf(pr[0], pr[1]), fmaxf(pr[2], pr[3]));
    float s = 0.f, ex[EE];
    for (int e2 = 0; e2 < EE; ++e2){ ex[e2] = __expf(pr[e2] - mx); s += ex[e2]; }
    for (int e2 = 0; e2 < EE; ++e2) gate[b * EE + e2] = ex[e2] / s;
  }
}

// ---------------- head precompute: A = headW @ proj_W, c = headW.proj_b + head_b ----------------
__global__ __launch_bounds__(256) void k_headpre(const float* __restrict__ efW,
                                                 const float* __restrict__ efb,
                                                 const float* __restrict__ edW,
                                                 const float* __restrict__ edb,
                                                 const float* __restrict__ projW,
                                                 const float* __restrict__ projb,
                                                 float* __restrict__ Acomb,
                                                 float* __restrict__ Ccomb){
  int head = blockIdx.x >> 2, e2 = blockIdx.x & 3, tid = threadIdx.x;
  const float* Wv = head ? edW : efW;
  const float* bv = head ? edb : efb;
  __shared__ float wrow[HH];
  for (int i = tid; i < HH; i += 256) wrow[i] = Wv[e2 * HH + i];
  __syncthreads();
  for (int c = tid; c < HH; c += 256){
    float a = 0.f;
    for (int h2 = 0; h2 < HH; ++h2) a += wrow[h2] * projW[(size_t)h2 * HH + c];
    Acomb[(head * 4 + e2) * HH + c] = a;
  }
  int wv = tid >> 6, lane = tid & 63;
  if (wv == 0){
    float p = 0.f;
    for (int k = lane; k < HH; k += 64) p += wrow[k] * projb[k];
#pragma unroll
    for (int off = 32; off; off >>= 1) p += __shfl_down(p, off);
    if (lane == 0) Ccomb[head * 4 + e2] = p + bv[e2];
  }
}

// ---------------- fused expert heads: out = sum_e gate * (hcat.A_e + c_e) ----------------
__global__ __launch_bounds__(256) void k_heads(const short* __restrict__ hcat,
                                               const float* __restrict__ Acomb,
                                               const float* __restrict__ Ccomb,
                                               const float* __restrict__ gate,
                                               float* __restrict__ outp){
  __shared__ float Al[8 * HH];   // 24 KB
  int tid = threadIdx.x;
  for (int i = tid; i < 8 * HH; i += 256) Al[i] = Acomb[i];
  __syncthreads();
  int wv = tid >> 6, lane = tid & 63;
  int bw = blockIdx.x * 4 + wv;        // = b*512 + w
  const short* hr = hcat + (size_t)bw * HH;
  float hv[12];
#pragma unroll
  for (int j = 0; j < 12; ++j) hv[j] = bf2f(hr[lane + 64 * j]);
  float dsum[8];
#pragma unroll
  for (int v = 0; v < 8; ++v){
    float p = 0.f;
#pragma unroll
    for (int j = 0; j < 12; ++j) p += hv[j] * Al[v * HH + lane + 64 * j];
#pragma unroll
    for (int off = 32; off; off >>= 1) p += __shfl_xor(p, off);
    dsum[v] = p;
  }
  if (lane == 0){
    int b = bw >> 9;
    float fx = 0.f, du = 0.f;
#pragma unroll
    for (int e2 = 0; e2 < 4; ++e2){
      float g = gate[b * 4 + e2];
      fx += g * (dsum[e2]     + Ccomb[e2]);
      du += g * (dsum[4 + e2] + Ccomb[4 + e2]);
    }
    outp[bw] = fx;
    outp[BB * NW + bw] = du;
  }
}

extern "C" void kernel_launch(void* const* d_in, const int* in_sizes, int n_in,
                              void* d_out, int out_size, void* d_ws, size_t ws_size,
                              hipStream_t stream){
  const float* tok   = (const float*)d_in[0];
  const int*   wmap  = (const int*)d_in[1];
  const int*   lids  = (const int*)d_in[2];
  const float* Wih_f = (const float*)d_in[3];
  const float* Whh_f = (const float*)d_in[4];
  const float* bih_f = (const float*)d_in[5];
  const float* bhh_f = (const float*)d_in[6];
  const float* Wih_b = (const float*)d_in[7];
  const float* Whh_b = (const float*)d_in[8];
  const float* bih_b = (const float*)d_in[9];
  const float* bhh_b = (const float*)d_in[10];
  const float* projW = (const float*)d_in[11];
  const float* projb = (const float*)d_in[12];
  const float* ltab  = (const float*)d_in[13];
  const float* gW1   = (const float*)d_in[14];
  const float* gb1   = (const float*)d_in[15];
  const float* gW2   = (const float*)d_in[16];
  const float* gb2   = (const float*)d_in[17];
  const float* efW   = (const float*)d_in[18];
  const float* efb   = (const float*)d_in[19];
  const float* edW   = (const float*)d_in[20];
  const float* edb   = (const float*)d_in[21];
  float* outp = (float*)d_out;

  char* ws = (char*)d_ws;
  size_t off = 0;
  auto alloc = [&](size_t bytes) -> char* {
    char* p = ws + off;
    off = (off + bytes + 255) & ~(size_t)255;
    return p;
  };
  short* we_bf   = (short*)alloc((size_t)BB * NW * HH * 2);
  short* wihf_bf = (short*)alloc((size_t)G4 * HH * 2);
  short* wihb_bf = (short*)alloc((size_t)G4 * HH * 2);
  short* whhf_bf = (short*)alloc((size_t)G4 * HID * 2);
  short* whhb_bf = (short*)alloc((size_t)G4 * HID * 2);
  float* xg_f    = (float*)alloc((size_t)BB * NW * G4 * 4);
  float* xg_b    = (float*)alloc((size_t)BB * NW * G4 * 4);
  short* hcat    = (short*)alloc((size_t)BB * NW * HH * 2);
  short* hbuf    = (short*)alloc((size_t)2 * 2 * BB * HID * 2);
  int*   flags   = (int*)alloc((size_t)2 * NW * 16 * 4);
  float* gateb   = (float*)alloc((size_t)BB * EE * 4);
  float* Acomb   = (float*)alloc((size_t)8 * HH * 4);
  float* Ccomb   = (float*)alloc((size_t)8 * 4);

  int nflag = 2 * NW * 16;
  k_zero<<<(nflag + 255) / 256, 256, 0, stream>>>(flags, nflag);
  k_f2bf<<<1024, 256, 0, stream>>>(Wih_f, wihf_bf, G4 * HH);
  k_f2bf<<<1024, 256, 0, stream>>>(Wih_b, wihb_bf, G4 * HH);
  k_f2bf<<<512, 256, 0, stream>>>(Whh_f, whhf_bf, G4 * HID);
  k_f2bf<<<512, 256, 0, stream>>>(Whh_b, whhb_bf, G4 * HID);
  k_segmean<<<BB * NW, 256, 0, stream>>>(tok, wmap, we_bf);
  k_gemm_bt<<<(BB * NW / 128) * (G4 / 128), 256, 0, stream>>>(we_bf, wihf_bf, bih_f, bhh_f, xg_f, BB * NW, G4, HH);
  k_gemm_bt<<<(BB * NW / 128) * (G4 / 128), 256, 0, stream>>>(we_bf, wihb_bf, bih_b, bhh_b, xg_b, BB * NW, G4, HH);
  k_gate<<<BB, 256, 0, stream>>>(tok, lids, ltab, gW1, gb1, gW2, gb2, gateb);
  k_headpre<<<8, 256, 0, stream>>>(efW, efb, edW, edb, projW, projb, Acomb, Ccomb);
  k_lstm<<<2 * CWG, 512, 0, stream>>>(xg_f, xg_b, whhf_bf, whhb_bf, hbuf, hcat, flags);
  k_heads<<<(BB * NW) / 4, 256, 0, stream>>>(hcat, Acomb, Ccomb, gateb, outp);
}

// Round 6
// 2610.727 us; speedup vs baseline: 1.2610x; 1.2610x over previous
//
#include <hip/hip_runtime.h>
#include <stdint.h>

#define BB 32
#define LL 1024
#define NW 512
#define HH 768
#define HID 384
#define G4 1536   // 4*HID
#define EE 4
#define DLL 128
#define GIN 896   // H+DL
#define CWG 12    // column-group WGs per direction
#define WGC 32    // h-cols per WG
#define HPAD 392  // padded LDS row stride (shorts)

typedef __attribute__((ext_vector_type(8))) short short8;
typedef __attribute__((ext_vector_type(4))) float f32x4;

__device__ __forceinline__ float bf2f(short s){
  union { unsigned int u; float f; } v; v.u = ((unsigned int)(unsigned short)s) << 16; return v.f;
}
__device__ __forceinline__ short f2bf(float f){
  union { float f; unsigned int u; } v; v.f = f;
  unsigned int r = v.u + 0x7fffu + ((v.u >> 16) & 1u);
  return (short)(r >> 16);
}
__device__ __forceinline__ float sigm(float x){ return 1.f / (1.f + __expf(-x)); }
__device__ __forceinline__ float ftanh(float x){ float e = __expf(2.f * x); return 1.f - 2.f / (e + 1.f); }

__device__ __forceinline__ void gload16(const void* g, void* l){
  __builtin_amdgcn_global_load_lds(
      (const __attribute__((address_space(1))) unsigned int*)g,
      (__attribute__((address_space(3))) unsigned int*)l, 16, 0, 0);
}

// ---------------- zero flags ----------------
__global__ void k_zero(int* flags, int n){
  int i = blockIdx.x * 256 + threadIdx.x;
  if (i < n) flags[i] = 0;
}

// ---------------- f32 -> bf16 convert ----------------
__global__ void k_f2bf(const float* in, short* out, int n){
  int i = blockIdx.x * blockDim.x + threadIdx.x;
  int st = gridDim.x * blockDim.x;
  for (; i < n; i += st) out[i] = f2bf(in[i]);
}

// ---------------- segment mean pooling ----------------
__global__ __launch_bounds__(256) void k_segmean(const float* __restrict__ tok,
                                                 const int* __restrict__ wmap,
                                                 short* __restrict__ we_bf){
  int blk = blockIdx.x;
  int b = blk >> 9;          // / NW
  int w = blk & 511;
  const int* m = wmap + b * LL;
  int lo = 0, hi = LL;
  while (lo < hi){ int mid = (lo + hi) >> 1; if (m[mid] < w) lo = mid + 1; else hi = mid; }
  int s = lo;
  int lo2 = s, hi2 = LL;
  while (lo2 < hi2){ int mid = (lo2 + hi2) >> 1; if (m[mid] <= w) lo2 = mid + 1; else hi2 = mid; }
  int e = lo2;
  float cnt = (float)(e - s);
  float denom = fmaxf(cnt, 1.f);
  for (int j = threadIdx.x; j < HH; j += 256){
    float acc = 0.f;
    for (int r = s; r < e; ++r) acc += tok[((size_t)b * LL + r) * HH + j];
    we_bf[((size_t)b * NW + w) * HH + j] = f2bf(acc / denom);
  }
}

// ---------------- GEMM: C[M,N] = A[M,K](bf16) * W[N,K]^T(bf16) + b1[n] + b2[n] ----------------
__global__ __launch_bounds__(256) void k_gemm_bt(const short* __restrict__ Abf,
                                                 const short* __restrict__ Wbf,
                                                 const float* __restrict__ b1,
                                                 const float* __restrict__ b2,
                                                 float* __restrict__ Cf,
                                                 int M, int N, int K){
  __shared__ __attribute__((aligned(16))) short As[128 * 32];
  __shared__ __attribute__((aligned(16))) short Bs[128 * 32];
  int ntiles = N >> 7;
  int m0 = (blockIdx.x / ntiles) << 7;
  int n0 = (blockIdx.x % ntiles) << 7;
  int tid = threadIdx.x, lane = tid & 63, wv = tid >> 6;
  int wm = (wv >> 1) << 6, wn = (wv & 1) << 6;
  f32x4 acc[4][4] = {};
  for (int kk = 0; kk < K; kk += 32){
#pragma unroll
    for (int q = 0; q < 2; ++q){
      int e = q * 256 + tid;        // 16B granule: row = e/4, col = (e&3)*8 shorts
      int row = e >> 2, col = (e & 3) << 3;
      gload16(Abf + (size_t)(m0 + row) * K + kk + col, As + e * 8);
      gload16(Wbf + (size_t)(n0 + row) * K + kk + col, Bs + e * 8);
    }
    __syncthreads();
    short8 af[4], bfr[4];
#pragma unroll
    for (int x = 0; x < 4; ++x){
      af[x]  = *(const short8*)(As + (wm + x * 16 + (lane & 15)) * 32 + ((lane >> 4) << 3));
      bfr[x] = *(const short8*)(Bs + (wn + x * 16 + (lane & 15)) * 32 + ((lane >> 4) << 3));
    }
#pragma unroll
    for (int x = 0; x < 4; ++x)
#pragma unroll
      for (int y = 0; y < 4; ++y)
        acc[x][y] = __builtin_amdgcn_mfma_f32_16x16x32_bf16(af[x], bfr[y], acc[x][y], 0, 0, 0);
    __syncthreads();
  }
#pragma unroll
  for (int x = 0; x < 4; ++x)
#pragma unroll
    for (int y = 0; y < 4; ++y)
#pragma unroll
      for (int i = 0; i < 4; ++i){
        int mm = m0 + wm + x * 16 + ((lane >> 4) << 2) + i;
        int nn = n0 + wn + y * 16 + (lane & 15);
        Cf[(size_t)mm * N + nn] = acc[x][y][i] + b1[nn] + b2[nn];
      }
}

// ---------------- BiLSTM: persistent, batch-split 2-tick pipeline ----------------
// 12 WGs/dir x 512 threads. Batch split into halves of 16; ticks alternate halves so
// each half's store->flag->poll->load chain hides behind the other half's tick.
// Flag publication piggybacks on next tick's start-drain; prefetches cross raw barriers.
__global__ __launch_bounds__(512) void k_lstm(const float* __restrict__ xg_f,
                                              const float* __restrict__ xg_b,
                                              const short* __restrict__ whh_f,
                                              const short* __restrict__ whh_b,
                                              short* __restrict__ hbuf,
                                              short* __restrict__ hcat,
                                              int* __restrict__ flags){
  int bx = blockIdx.x;
  int dir = bx / CWG;
  int cg  = bx % CWG;
  int tid = threadIdx.x, lane = tid & 63, wv = tid >> 6;
  int q = lane >> 4, fr = lane & 15;
  int g = wv >> 1, nh = wv & 1;                // gate, 16-col half of WG's 32 cols
  int jbase = g * HID + cg * WGC + nh * 16;
  const float* xg  = dir ? xg_b : xg_f;
  const short* whh = dir ? whh_b : whh_f;

  // resident Whh B-fragments: 16 gate-rows x K=384 -> 12 k-steps, 48 VGPRs
  short8 bfrag[12];
  {
    const short* wr = whh + (size_t)(jbase + fr) * HID + q * 8;
#pragma unroll
    for (int ks = 0; ks < 12; ++ks) bfrag[ks] = *(const short8*)(wr + ks * 32);
  }

  __shared__ __attribute__((aligned(16))) short hs[2][16 * HPAD];  // per-half staged h
  __shared__ float pre[4][16][34];                                 // conflict-free preacts

  float c0s = 0.f, c1s = 0.f;                  // cell state per half (this thread's cell)
  int eb = tid >> 5, ecol = tid & 31;          // elementwise: 1 cell/thread
  int pc = fr;                                 // poll lane
  int* flgD = flags + (size_t)dir * 2 * NW * 16;
  short* hbD = hbuf + (size_t)dir * 2 * 2 * 16 * HID;

  float xgv[4], nxg[4];
  {
    int t0a = dir ? (NW - 1) : 0;              // prologue xg for tick (half0, t=0)
#pragma unroll
    for (int i = 0; i < 4; ++i)
      xgv[i] = xg[((size_t)(q * 4 + i) * NW + t0a) * G4 + jbase + fr];
  }
  short8 sv0, sv1;
  int probe_v = 0;

  for (int tt = 0; tt < 2 * NW; ++tt){
    int half = tt & 1, t = tt >> 1;
    int t_act = dir ? (NW - 1 - t) : t;
    // tick start: drain prefetched data + previous tick's h stores (double duty)
    asm volatile("s_waitcnt vmcnt(0)" ::: "memory");
    __builtin_amdgcn_sched_barrier(0);
    if (tt > 0){
#pragma unroll
      for (int i = 0; i < 4; ++i) xgv[i] = nxg[i];
    }
    if (t > 0){
      int gi0 = tid;
      *(short8*)(&hs[half][(gi0 / 48) * HPAD + (gi0 % 48) * 8]) = sv0;
      if (tid < 256){
        int gi1 = 512 + tid;
        *(short8*)(&hs[half][(gi1 / 48) * HPAD + (gi1 % 48) * 8]) = sv1;
      }
    }
    asm volatile("s_waitcnt lgkmcnt(0)" ::: "memory");
    __builtin_amdgcn_s_barrier();              // barrier A (staging + store-ack complete)
    __builtin_amdgcn_sched_barrier(0);
    if (tt > 0 && tid == 0){                   // publish previous tick's flag
      int ph = 1 - half;
      int pt2 = (tt - 1) >> 1;
      int one = 1;
      int* fs = flgD + ((size_t)ph * NW + pt2) * 16 + cg;
      asm volatile("global_store_dword %0, %1, off sc0 sc1" :: "v"(fs), "v"(one) : "memory");
    }
    int Y = 1 - half;
    int tY = half ? (t + 1) : t;               // next tick = (Y, tY)
    bool do_next = (tY < NW);
    bool do_poll = do_next && (tY > 0);
    const int* fp = flgD + ((size_t)Y * NW + (tY - 1)) * 16 + pc;
    if (do_poll)                               // probe flies under MFMA
      asm volatile("global_load_dword %0, %1, off sc0 sc1" : "=v"(probe_v) : "v"(fp) : "memory");
    // MFMA for current tick (M=16 half-batch)
    f32x4 acc = {}, accB = {};
    if (t > 0){
      const short* hrow = &hs[half][fr * HPAD + q * 8];
#pragma unroll
      for (int ks = 0; ks < 6; ++ks)
        acc = __builtin_amdgcn_mfma_f32_16x16x32_bf16(*(const short8*)(hrow + ks * 32), bfrag[ks], acc, 0, 0, 0);
#pragma unroll
      for (int ks = 6; ks < 12; ++ks)
        accB = __builtin_amdgcn_mfma_f32_16x16x32_bf16(*(const short8*)(hrow + ks * 32), bfrag[ks], accB, 0, 0, 0);
      acc += accB;
    }
#pragma unroll
    for (int i = 0; i < 4; ++i)
      pre[g][q * 4 + i][nh * 16 + fr] = acc[i] + xgv[i];
    // probe check + retry
    if (do_poll){
      asm volatile("s_waitcnt vmcnt(0)" ::: "memory");
      __builtin_amdgcn_sched_barrier(0);
      while (!__all(probe_v != 0 || pc >= CWG)){
        __builtin_amdgcn_s_sleep(1);
        asm volatile("global_load_dword %0, %1, off sc0 sc1" : "=v"(probe_v) : "v"(fp) : "memory");
        asm volatile("s_waitcnt vmcnt(0)" ::: "memory");
        __builtin_amdgcn_sched_barrier(0);
      }
    }
    // prefetch next tick's h + xg (arrives during elementwise/stores + next drain)
    if (do_next){
      if (tY > 0){
        const short* hp = hbD + ((size_t)Y * 2 + ((tY - 1) & 1)) * 16 * HID;
        const short* s0 = hp + tid * 8;
        asm volatile("global_load_dwordx4 %0, %1, off sc0 sc1" : "=v"(sv0) : "v"(s0) : "memory");
        if (tid < 256){
          const short* s1 = hp + (512 + tid) * 8;
          asm volatile("global_load_dwordx4 %0, %1, off sc0 sc1" : "=v"(sv1) : "v"(s1) : "memory");
        }
      }
      int tYa = dir ? (NW - 1 - tY) : tY;
#pragma unroll
      for (int i = 0; i < 4; ++i)
        nxg[i] = xg[((size_t)(Y * 16 + q * 4 + i) * NW + tYa) * G4 + jbase + fr];
    }
    asm volatile("s_waitcnt lgkmcnt(0)" ::: "memory");
    __builtin_amdgcn_s_barrier();              // barrier B (preacts ready)
    __builtin_amdgcn_sched_barrier(0);
    // elementwise: 1 cell/thread, conflict-free pre[] reads
    float gi2 = pre[0][eb][ecol], gf2 = pre[1][eb][ecol];
    float gg2 = pre[2][eb][ecol], go2 = pre[3][eb][ecol];
    float c = half ? c1s : c0s;
    c = sigm(gf2) * c + sigm(gi2) * ftanh(gg2);
    float h = sigm(go2) * ftanh(c);
    if (half) c1s = c; else c0s = c;
    unsigned int hv = (unsigned int)(unsigned short)f2bf(h);
    short* hw = hbD + ((size_t)half * 2 + (t & 1)) * 16 * HID + eb * HID + cg * WGC + ecol;
    asm volatile("global_store_short %0, %1, off sc0 sc1" :: "v"(hw), "v"(hv) : "memory");
    hcat[((size_t)(half * 16 + eb) * NW + t_act) * HH + dir * HID + cg * WGC + ecol] = (short)hv;
    // stores ack'd by NEXT tick's start-drain; flag published after its barrier A
  }
}

// ---------------- gate MLP + softmax (per batch row) ----------------
__global__ __launch_bounds__(256) void k_gate(const float* __restrict__ tok,
                                              const int* __restrict__ lids,
                                              const float* __restrict__ ltab,
                                              const float* __restrict__ W1,
                                              const float* __restrict__ b1v,
                                              const float* __restrict__ W2,
                                              const float* __restrict__ b2v,
                                              float* __restrict__ gate){
  __shared__ float gin[GIN];
  __shared__ float hid[HH];
  __shared__ float pr[EE];
  int b = blockIdx.x, tid = threadIdx.x;
  int lid = lids[b];
  for (int i = tid; i < GIN; i += 256)
    gin[i] = (i < HH) ? tok[(size_t)b * LL * HH + i] : ltab[lid * DLL + (i - HH)];
  __syncthreads();
  for (int j = tid; j < HH; j += 256){
    float a = b1v[j];
    const float* wr = W1 + (size_t)j * GIN;
    for (int k = 0; k < GIN; ++k) a += gin[k] * wr[k];
    hid[j] = fmaxf(a, 0.f);
  }
  __syncthreads();
  int wv = tid >> 6, lane = tid & 63;
  if (wv < EE){
    float p = 0.f;
    for (int k = lane; k < HH; k += 64) p += hid[k] * W2[wv * HH + k];
#pragma unroll
    for (int off = 32; off; off >>= 1) p += __shfl_down(p, off);
    if (lane == 0) pr[wv] = p + b2v[wv];
  }
  __syncthreads();
  if (tid == 0){
    float mx = fmaxf(fmaxf(pr[0], pr[1]), fmaxf(pr[2], pr[3]));
    float s = 0.f, ex[EE];
    for (int e2 = 0; e2 < EE; ++e2){ ex[e2] = __expf(pr[e2] - mx); s += ex[e2]; }
    for (int e2 = 0; e2 < EE; ++e2) gate[b * EE + e2] = ex[e2] / s;
  }
}

// ---------------- head precompute: A = headW @ proj_W, c = headW.proj_b + head_b ----------------
__global__ __launch_bounds__(256) void k_headpre(const float* __restrict__ efW,
                                                 const float* __restrict__ efb,
                                                 const float* __restrict__ edW,
                                                 const float* __restrict__ edb,
                                                 const float* __restrict__ projW,
                                                 const float* __restrict__ projb,
                                                 float* __restrict__ Acomb,
                                                 float* __restrict__ Ccomb){
  int head = blockIdx.x >> 2, e2 = blockIdx.x & 3, tid = threadIdx.x;
  const float* Wv = head ? edW : efW;
  const float* bv = head ? edb : efb;
  __shared__ float wrow[HH];
  for (int i = tid; i < HH; i += 256) wrow[i] = Wv[e2 * HH + i];
  __syncthreads();
  for (int c = tid; c < HH; c += 256){
    float a = 0.f;
    for (int h2 = 0; h2 < HH; ++h2) a += wrow[h2] * projW[(size_t)h2 * HH + c];
    Acomb[(head * 4 + e2) * HH + c] = a;
  }
  int wv = tid >> 6, lane = tid & 63;
  if (wv == 0){
    float p = 0.f;
    for (int k = lane; k < HH; k += 64) p += wrow[k] * projb[k];
#pragma unroll
    for (int off = 32; off; off >>= 1) p += __shfl_down(p, off);
    if (lane == 0) Ccomb[head * 4 + e2] = p + bv[e2];
  }
}

// ---------------- fused expert heads: out = sum_e gate * (hcat.A_e + c_e) ----------------
__global__ __launch_bounds__(256) void k_heads(const short* __restrict__ hcat,
                                               const float* __restrict__ Acomb,
                                               const float* __restrict__ Ccomb,
                                               const float* __restrict__ gate,
                                               float* __restrict__ outp){
  __shared__ float Al[8 * HH];   // 24 KB
  int tid = threadIdx.x;
  for (int i = tid; i < 8 * HH; i += 256) Al[i] = Acomb[i];
  __syncthreads();
  int wv = tid >> 6, lane = tid & 63;
  int bw = blockIdx.x * 4 + wv;        // = b*512 + w
  const short* hr = hcat + (size_t)bw * HH;
  float hv[12];
#pragma unroll
  for (int j = 0; j < 12; ++j) hv[j] = bf2f(hr[lane + 64 * j]);
  float dsum[8];
#pragma unroll
  for (int v = 0; v < 8; ++v){
    float p = 0.f;
#pragma unroll
    for (int j = 0; j < 12; ++j) p += hv[j] * Al[v * HH + lane + 64 * j];
#pragma unroll
    for (int off = 32; off; off >>= 1) p += __shfl_xor(p, off);
    dsum[v] = p;
  }
  if (lane == 0){
    int b = bw >> 9;
    float fx = 0.f, du = 0.f;
#pragma unroll
    for (int e2 = 0; e2 < 4; ++e2){
      float g = gate[b * 4 + e2];
      fx += g * (dsum[e2]     + Ccomb[e2]);
      du += g * (dsum[4 + e2] + Ccomb[4 + e2]);
    }
    outp[bw] = fx;
    outp[BB * NW + bw] = du;
  }
}

extern "C" void kernel_launch(void* const* d_in, const int* in_sizes, int n_in,
                              void* d_out, int out_size, void* d_ws, size_t ws_size,
                              hipStream_t stream){
  const float* tok   = (const float*)d_in[0];
  const int*   wmap  = (const int*)d_in[1];
  const int*   lids  = (const int*)d_in[2];
  const float* Wih_f = (const float*)d_in[3];
  const float* Whh_f = (const float*)d_in[4];
  const float* bih_f = (const float*)d_in[5];
  const float* bhh_f = (const float*)d_in[6];
  const float* Wih_b = (const float*)d_in[7];
  const float* Whh_b = (const float*)d_in[8];
  const float* bih_b = (const float*)d_in[9];
  const float* bhh_b = (const float*)d_in[10];
  const float* projW = (const float*)d_in[11];
  const float* projb = (const float*)d_in[12];
  const float* ltab  = (const float*)d_in[13];
  const float* gW1   = (const float*)d_in[14];
  const float* gb1   = (const float*)d_in[15];
  const float* gW2   = (const float*)d_in[16];
  const float* gb2   = (const float*)d_in[17];
  const float* efW   = (const float*)d_in[18];
  const float* efb   = (const float*)d_in[19];
  const float* edW   = (const float*)d_in[20];
  const float* edb   = (const float*)d_in[21];
  float* outp = (float*)d_out;

  char* ws = (char*)d_ws;
  size_t off = 0;
  auto alloc = [&](size_t bytes) -> char* {
    char* p = ws + off;
    off = (off + bytes + 255) & ~(size_t)255;
    return p;
  };
  short* we_bf   = (short*)alloc((size_t)BB * NW * HH * 2);
  short* wihf_bf = (short*)alloc((size_t)G4 * HH * 2);
  short* wihb_bf = (short*)alloc((size_t)G4 * HH * 2);
  short* whhf_bf = (short*)alloc((size_t)G4 * HID * 2);
  short* whhb_bf = (short*)alloc((size_t)G4 * HID * 2);
  float* xg_f    = (float*)alloc((size_t)BB * NW * G4 * 4);
  float* xg_b    = (float*)alloc((size_t)BB * NW * G4 * 4);
  short* hcat    = (short*)alloc((size_t)BB * NW * HH * 2);
  short* hbuf    = (short*)alloc((size_t)2 * 2 * 2 * 16 * HID * 2);
  int*   flags   = (int*)alloc((size_t)2 * 2 * NW * 16 * 4);
  float* gateb   = (float*)alloc((size_t)BB * EE * 4);
  float* Acomb   = (float*)alloc((size_t)8 * HH * 4);
  float* Ccomb   = (float*)alloc((size_t)8 * 4);

  int nflag = 2 * 2 * NW * 16;
  k_zero<<<(nflag + 255) / 256, 256, 0, stream>>>(flags, nflag);
  k_f2bf<<<1024, 256, 0, stream>>>(Wih_f, wihf_bf, G4 * HH);
  k_f2bf<<<1024, 256, 0, stream>>>(Wih_b, wihb_bf, G4 * HH);
  k_f2bf<<<512, 256, 0, stream>>>(Whh_f, whhf_bf, G4 * HID);
  k_f2bf<<<512, 256, 0, stream>>>(Whh_b, whhb_bf, G4 * HID);
  k_segmean<<<BB * NW, 256, 0, stream>>>(tok, wmap, we_bf);
  k_gemm_bt<<<(BB * NW / 128) * (G4 / 128), 256, 0, stream>>>(we_bf, wihf_bf, bih_f, bhh_f, xg_f, BB * NW, G4, HH);
  k_gemm_bt<<<(BB * NW / 128) * (G4 / 128), 256, 0, stream>>>(we_bf, wihb_bf, bih_b, bhh_b, xg_b, BB * NW, G4, HH);
  k_gate<<<BB, 256, 0, stream>>>(tok, lids, ltab, gW1, gb1, gW2, gb2, gateb);
  k_headpre<<<8, 256, 0, stream>>>(efW, efb, edW, edb, projW, projb, Acomb, Ccomb);
  k_lstm<<<2 * CWG, 512, 0, stream>>>(xg_f, xg_b, whhf_bf, whhb_bf, hbuf, hcat, flags);
  k_heads<<<(BB * NW) / 4, 256, 0, stream>>>(hcat, Acomb, Ccomb, gateb, outp);
}